// Round 3
// baseline (72.574 us; speedup 1.0000x reference)
//
#include <hip/hip_runtime.h>

#define NF 8
#define NA 14
#define FT 4      // frames per work block (must divide NF)
#define SPLIT 2   // atom-range splits per frame group
#define D_CLAMP 10.0f
#define FAPE_EPS 1e-4f
#define ZINV 0.1f

// ws layout (bytes): [0,4) counter | [128,128+8b) acfc | [4096, ...) partial
__global__ __launch_bounds__(256, 3) void fape_fused(
    const float* __restrict__ predR,   // (b, N*NF, 3, 3)
    const float* __restrict__ predT,   // (b, N*NF, 3)
    const float* __restrict__ predPos, // (b, N*NA, 3)
    const float* __restrict__ atomMask,// (b, N*NA)
    const float* __restrict__ trueR,
    const float* __restrict__ trueT,
    const float* __restrict__ truePos,
    const float* __restrict__ seqMask, // (b, N)
    float* __restrict__ partial,       // [workBlocks] one float per work block
    float* __restrict__ acfc,          // [2*b] atom_count, frame_count_raw
    unsigned int* __restrict__ counter,
    float* __restrict__ out,
    int N, int b, int workBlocks)
{
    const int tid = threadIdx.x;
    const int bid = blockIdx.x;
    const int nAtoms    = N * NA;
    const int nFramesPB = N * NF;

    __shared__ float sRed[4];
    __shared__ float sRed2[4];
    __shared__ bool  sLast;

    if (bid < workBlocks) {
        // ---------------- work block: FT frames x atom slice ----------------
        const int fgrp  = bid / SPLIT;
        const int sp    = bid - fgrp * SPLIT;
        const int fg0   = fgrp * FT;
        const int batch = fg0 / nFramesPB;
        const int res   = (fg0 - batch * nFramesPB) / NF; // residue of this group

        // Block-uniform frame constants (scalar loads); pre-negate true side
        float rp[FT][9], rtn[FT][9], offn[FT][3];
#pragma unroll
        for (int k = 0; k < FT; ++k) {
            const float* Rp = predR + (size_t)(fg0 + k) * 9;
            const float* Rt = trueR + (size_t)(fg0 + k) * 9;
            const float* tp = predT + (size_t)(fg0 + k) * 3;
            const float* tt = trueT + (size_t)(fg0 + k) * 3;
#pragma unroll
            for (int i = 0; i < 9; ++i) { rp[k][i] = Rp[i]; rtn[k][i] = -Rt[i]; }
            const float tp0 = tp[0], tp1 = tp[1], tp2 = tp[2];
            const float tt0 = tt[0], tt1 = tt[1], tt2 = tt[2];
#pragma unroll
            for (int i = 0; i < 3; ++i) {
                // offn = -(Rp^T tp) + (Rt^T tt)
                offn[k][i] = -(rp[k][i]*tp0 + rp[k][3+i]*tp1 + rp[k][6+i]*tp2)
                             -(rtn[k][i]*tt0 + rtn[k][3+i]*tt1 + rtn[k][6+i]*tt2);
            }
        }

        const float* pP  = predPos  + (size_t)batch * nAtoms * 3;
        const float* tP  = truePos  + (size_t)batch * nAtoms * 3;
        const float* aMb = atomMask + (size_t)batch * nAtoms;
        const float* sMb = seqMask  + (size_t)batch * N;
        const float  w   = sMb[res];

        const int aBeg = (nAtoms * sp) / SPLIT;       // multiples of 4
        const int aEnd = (nAtoms * (sp + 1)) / SPLIT;

        float acc = 0.0f;

        auto pair = [&](float pp0, float pp1, float pp2,
                        float pt0, float pt1, float pt2, float m) {
#pragma unroll
            for (int k = 0; k < FT; ++k) {
                float d0 = offn[k][0] + rp[k][0]*pp0 + rp[k][3]*pp1 + rp[k][6]*pp2
                                      + rtn[k][0]*pt0 + rtn[k][3]*pt1 + rtn[k][6]*pt2;
                float d1 = offn[k][1] + rp[k][1]*pp0 + rp[k][4]*pp1 + rp[k][7]*pp2
                                      + rtn[k][1]*pt0 + rtn[k][4]*pt1 + rtn[k][7]*pt2;
                float d2 = offn[k][2] + rp[k][2]*pp0 + rp[k][5]*pp1 + rp[k][8]*pp2
                                      + rtn[k][2]*pt0 + rtn[k][5]*pt1 + rtn[k][8]*pt2;
                float ns = d0*d0 + d1*d1 + d2*d2 + FAPE_EPS;
                acc += fminf(__builtin_amdgcn_sqrtf(ns), D_CLAMP) * m;
            }
        };

        for (int a0 = aBeg + (tid << 2); a0 < aEnd; a0 += 1024) {
            const float4 P0 = *reinterpret_cast<const float4*>(pP + 3*a0);
            const float4 P1 = *reinterpret_cast<const float4*>(pP + 3*a0 + 4);
            const float4 P2 = *reinterpret_cast<const float4*>(pP + 3*a0 + 8);
            const float4 Q0 = *reinterpret_cast<const float4*>(tP + 3*a0);
            const float4 Q1 = *reinterpret_cast<const float4*>(tP + 3*a0 + 4);
            const float4 Q2 = *reinterpret_cast<const float4*>(tP + 3*a0 + 8);
            const float4 AM = *reinterpret_cast<const float4*>(aMb + a0);

            const int q   = a0 / NA;
            const int rem = a0 - q * NA;
            const float m0 = AM.x * sMb[q];
            const float m1 = AM.y * sMb[q + ((rem + 1) >= NA ? 1 : 0)];
            const float m2 = AM.z * sMb[q + ((rem + 2) >= NA ? 1 : 0)];
            const float m3 = AM.w * sMb[q + ((rem + 3) >= NA ? 1 : 0)];

            pair(P0.x, P0.y, P0.z,  Q0.x, Q0.y, Q0.z,  m0);
            pair(P0.w, P1.x, P1.y,  Q0.w, Q1.x, Q1.y,  m1);
            pair(P1.z, P1.w, P2.x,  Q1.z, Q1.w, Q2.x,  m2);
            pair(P2.y, P2.z, P2.w,  Q2.y, Q2.z, Q2.w,  m3);
        }

#pragma unroll
        for (int o = 32; o > 0; o >>= 1) acc += __shfl_down(acc, o, 64);
        if ((tid & 63) == 0) sRed[tid >> 6] = acc;
        __syncthreads();
        if (tid == 0) {
            const float s = (sRed[0] + sRed[1] + sRed[2] + sRed[3]) * w;
            __hip_atomic_store(&partial[bid], s, __ATOMIC_RELAXED,
                               __HIP_MEMORY_SCOPE_AGENT);
        }
    } else {
        // -------------- mask block: atom_count & frame_count for one batch --
        const int batch = bid - workBlocks;
        const float* aMb = atomMask + (size_t)batch * nAtoms;
        const float* sMb = seqMask  + (size_t)batch * N;

        float ac = 0.0f, fc = 0.0f;
        for (int a0 = (tid << 2); a0 < nAtoms; a0 += 1024) {
            const float4 AM = *reinterpret_cast<const float4*>(aMb + a0);
            const int q   = a0 / NA;
            const int rem = a0 - q * NA;
            ac += AM.x * sMb[q]
                + AM.y * sMb[q + ((rem + 1) >= NA ? 1 : 0)]
                + AM.z * sMb[q + ((rem + 2) >= NA ? 1 : 0)]
                + AM.w * sMb[q + ((rem + 3) >= NA ? 1 : 0)];
        }
        for (int n = tid; n < N; n += 256) fc += sMb[n];

#pragma unroll
        for (int o = 32; o > 0; o >>= 1) {
            ac += __shfl_down(ac, o, 64);
            fc += __shfl_down(fc, o, 64);
        }
        if ((tid & 63) == 0) { sRed[tid >> 6] = ac; sRed2[tid >> 6] = fc; }
        __syncthreads();
        if (tid == 0) {
            __hip_atomic_store(&acfc[2*batch],
                               sRed[0]+sRed[1]+sRed[2]+sRed[3],
                               __ATOMIC_RELAXED, __HIP_MEMORY_SCOPE_AGENT);
            __hip_atomic_store(&acfc[2*batch+1],
                               sRed2[0]+sRed2[1]+sRed2[2]+sRed2[3],
                               __ATOMIC_RELAXED, __HIP_MEMORY_SCOPE_AGENT);
        }
    }

    // ---------------- completion protocol: last block reduces ----------------
    if (tid == 0) {
        __threadfence();  // release our partial/acfc store device-wide
        const unsigned old = __hip_atomic_fetch_add(counter, 1u,
                                 __ATOMIC_ACQ_REL, __HIP_MEMORY_SCOPE_AGENT);
        sLast = (old == (unsigned)(workBlocks + b - 1));
    }
    __syncthreads();
    if (!sLast) return;
    __threadfence();      // acquire: see everyone's stores

    const int blocksPerBatch = workBlocks / b;
    for (int batch = 0; batch < b; ++batch) {
        float s = 0.0f;
        for (int i = tid; i < blocksPerBatch; i += 256)
            s += __hip_atomic_load(&partial[(size_t)batch * blocksPerBatch + i],
                                   __ATOMIC_RELAXED, __HIP_MEMORY_SCOPE_AGENT);
#pragma unroll
        for (int o = 32; o > 0; o >>= 1) s += __shfl_down(s, o, 64);
        __syncthreads();                  // protect sRed reuse across phases
        if ((tid & 63) == 0) sRed[tid >> 6] = s;
        __syncthreads();
        if (tid == 0) {
            const float S  = sRed[0] + sRed[1] + sRed[2] + sRed[3];
            const float AC = fmaxf(__hip_atomic_load(&acfc[2*batch],
                                  __ATOMIC_RELAXED, __HIP_MEMORY_SCOPE_AGENT), 1.0f);
            const float FCr = __hip_atomic_load(&acfc[2*batch+1],
                                  __ATOMIC_RELAXED, __HIP_MEMORY_SCOPE_AGENT);
            const float FC = fmaxf(FCr * (float)NF, 1.0f);
            out[batch] = S / AC / FC * ZINV;
        }
    }
}

extern "C" void kernel_launch(void* const* d_in, const int* in_sizes, int n_in,
                              void* d_out, int out_size, void* d_ws, size_t ws_size,
                              hipStream_t stream) {
    const float* predR   = (const float*)d_in[0];
    const float* predT   = (const float*)d_in[1];
    const float* predPos = (const float*)d_in[2];
    const float* atomM   = (const float*)d_in[3];
    const float* trueR   = (const float*)d_in[4];
    const float* trueT   = (const float*)d_in[5];
    const float* truePos = (const float*)d_in[6];
    const float* seqM    = (const float*)d_in[7];
    float* out = (float*)d_out;

    const int b = out_size;                   // fape_loss has shape (b,)
    const int N = in_sizes[7] / b;            // seq_mask is (b, N)
    const int totalFrames = b * N * NF;
    const int workBlocks  = (totalFrames / FT) * SPLIT;

    unsigned int* counter = (unsigned int*)d_ws;
    float* acfc    = (float*)((char*)d_ws + 128);
    float* partial = (float*)((char*)d_ws + 4096);

    hipMemsetAsync(counter, 0, sizeof(unsigned int), stream);

    fape_fused<<<workBlocks + b, 256, 0, stream>>>(
        predR, predT, predPos, atomM, trueR, trueT, truePos, seqM,
        partial, acfc, counter, out, N, b, workBlocks);
}

// Round 4
// 37.390 us; speedup vs baseline: 1.9410x; 1.9410x over previous
//
#include <hip/hip_runtime.h>

#define NF 8
#define NA 14
#define FT 4      // frames per work block (must divide NF; FT<=NF/? keeps residue uniform)
#define SPLIT 2   // atom-range splits per frame group
#define D_CLAMP 10.0f
#define FAPE_EPS 1e-4f
#define ZINV 0.1f

// ws layout (bytes): [0, 4*b) S accumulators | [4096, 4096+8*b) acfc
__global__ __launch_bounds__(256) void fape_work(
    const float* __restrict__ predR,   // (b, N*NF, 3, 3)
    const float* __restrict__ predT,   // (b, N*NF, 3)
    const float* __restrict__ predPos, // (b, N*NA, 3)
    const float* __restrict__ atomMask,// (b, N*NA)
    const float* __restrict__ trueR,
    const float* __restrict__ trueT,
    const float* __restrict__ truePos,
    const float* __restrict__ seqMask, // (b, N)
    float* __restrict__ S,             // [b] weighted-sum accumulators (pre-zeroed)
    float* __restrict__ acfc,          // [2*b] atom_count, frame_count_raw
    int N, int workBlocks)
{
    const int tid = threadIdx.x;
    const int bid = blockIdx.x;
    const int nAtoms    = N * NA;
    const int nFramesPB = N * NF;

    __shared__ float sRed[4];
    __shared__ float sRed2[4];

    if (bid < workBlocks) {
        // ---------------- work block: FT frames x atom slice ----------------
        const int fgrp  = bid / SPLIT;
        const int sp    = bid - fgrp * SPLIT;
        const int fg0   = fgrp * FT;
        const int batch = fg0 / nFramesPB;
        const int res   = (fg0 - batch * nFramesPB) / NF; // residue (uniform over FT frames)

        // Block-uniform frame constants (scalar loads); pre-negate true side
        float rp[FT][9], rtn[FT][9], offn[FT][3];
#pragma unroll
        for (int k = 0; k < FT; ++k) {
            const float* Rp = predR + (size_t)(fg0 + k) * 9;
            const float* Rt = trueR + (size_t)(fg0 + k) * 9;
            const float* tp = predT + (size_t)(fg0 + k) * 3;
            const float* tt = trueT + (size_t)(fg0 + k) * 3;
#pragma unroll
            for (int i = 0; i < 9; ++i) { rp[k][i] = Rp[i]; rtn[k][i] = -Rt[i]; }
            const float tp0 = tp[0], tp1 = tp[1], tp2 = tp[2];
            const float tt0 = tt[0], tt1 = tt[1], tt2 = tt[2];
#pragma unroll
            for (int i = 0; i < 3; ++i) {
                offn[k][i] = -(rp[k][i]*tp0 + rp[k][3+i]*tp1 + rp[k][6+i]*tp2)
                             -(rtn[k][i]*tt0 + rtn[k][3+i]*tt1 + rtn[k][6+i]*tt2);
            }
        }

        const float* pP  = predPos  + (size_t)batch * nAtoms * 3;
        const float* tP  = truePos  + (size_t)batch * nAtoms * 3;
        const float* aMb = atomMask + (size_t)batch * nAtoms;
        const float* sMb = seqMask  + (size_t)batch * N;
        const float  w   = sMb[res];

        const int aBeg = (nAtoms * sp) / SPLIT;       // multiple of 4 for our shapes
        const int aEnd = (nAtoms * (sp + 1)) / SPLIT;

        float acc = 0.0f;

        auto pair = [&](float pp0, float pp1, float pp2,
                        float pt0, float pt1, float pt2, float m) {
#pragma unroll
            for (int k = 0; k < FT; ++k) {
                float d0 = offn[k][0] + rp[k][0]*pp0 + rp[k][3]*pp1 + rp[k][6]*pp2
                                      + rtn[k][0]*pt0 + rtn[k][3]*pt1 + rtn[k][6]*pt2;
                float d1 = offn[k][1] + rp[k][1]*pp0 + rp[k][4]*pp1 + rp[k][7]*pp2
                                      + rtn[k][1]*pt0 + rtn[k][4]*pt1 + rtn[k][7]*pt2;
                float d2 = offn[k][2] + rp[k][2]*pp0 + rp[k][5]*pp1 + rp[k][8]*pp2
                                      + rtn[k][2]*pt0 + rtn[k][5]*pt1 + rtn[k][8]*pt2;
                float ns = d0*d0 + d1*d1 + d2*d2 + FAPE_EPS;
                acc += fminf(__builtin_amdgcn_sqrtf(ns), D_CLAMP) * m;
            }
        };

        for (int a0 = aBeg + (tid << 2); a0 < aEnd; a0 += 1024) {
            const float4 P0 = *reinterpret_cast<const float4*>(pP + 3*a0);
            const float4 P1 = *reinterpret_cast<const float4*>(pP + 3*a0 + 4);
            const float4 P2 = *reinterpret_cast<const float4*>(pP + 3*a0 + 8);
            const float4 Q0 = *reinterpret_cast<const float4*>(tP + 3*a0);
            const float4 Q1 = *reinterpret_cast<const float4*>(tP + 3*a0 + 4);
            const float4 Q2 = *reinterpret_cast<const float4*>(tP + 3*a0 + 8);
            const float4 AM = *reinterpret_cast<const float4*>(aMb + a0);

            const int q   = a0 / NA;
            const int rem = a0 - q * NA;
            const float m0 = AM.x * sMb[q];
            const float m1 = AM.y * sMb[q + ((rem + 1) >= NA ? 1 : 0)];
            const float m2 = AM.z * sMb[q + ((rem + 2) >= NA ? 1 : 0)];
            const float m3 = AM.w * sMb[q + ((rem + 3) >= NA ? 1 : 0)];

            pair(P0.x, P0.y, P0.z,  Q0.x, Q0.y, Q0.z,  m0);
            pair(P0.w, P1.x, P1.y,  Q0.w, Q1.x, Q1.y,  m1);
            pair(P1.z, P1.w, P2.x,  Q1.z, Q1.w, Q2.x,  m2);
            pair(P2.y, P2.z, P2.w,  Q2.y, Q2.z, Q2.w,  m3);
        }

#pragma unroll
        for (int o = 32; o > 0; o >>= 1) acc += __shfl_down(acc, o, 64);
        if ((tid & 63) == 0) sRed[tid >> 6] = acc;
        __syncthreads();
        if (tid == 0) {
            // plain device-scope fp32 atomic add: no cache-maintenance ops
            atomicAdd(&S[batch], (sRed[0] + sRed[1] + sRed[2] + sRed[3]) * w);
        }
    } else {
        // -------------- mask block: atom_count & frame_count for one batch --
        const int batch = bid - workBlocks;
        const float* aMb = atomMask + (size_t)batch * nAtoms;
        const float* sMb = seqMask  + (size_t)batch * N;

        float ac = 0.0f, fc = 0.0f;
        for (int a0 = (tid << 2); a0 < nAtoms; a0 += 1024) {
            const float4 AM = *reinterpret_cast<const float4*>(aMb + a0);
            const int q   = a0 / NA;
            const int rem = a0 - q * NA;
            ac += AM.x * sMb[q]
                + AM.y * sMb[q + ((rem + 1) >= NA ? 1 : 0)]
                + AM.z * sMb[q + ((rem + 2) >= NA ? 1 : 0)]
                + AM.w * sMb[q + ((rem + 3) >= NA ? 1 : 0)];
        }
        for (int n = tid; n < N; n += 256) fc += sMb[n];

#pragma unroll
        for (int o = 32; o > 0; o >>= 1) {
            ac += __shfl_down(ac, o, 64);
            fc += __shfl_down(fc, o, 64);
        }
        if ((tid & 63) == 0) { sRed[tid >> 6] = ac; sRed2[tid >> 6] = fc; }
        __syncthreads();
        if (tid == 0) {
            acfc[2*batch]     = sRed[0] + sRed[1] + sRed[2] + sRed[3];
            acfc[2*batch + 1] = sRed2[0] + sRed2[1] + sRed2[2] + sRed2[3];
        }
    }
}

// Tiny finisher: one thread per batch. Inter-dispatch ordering guarantees
// visibility of kernel 1's atomics/stores.
__global__ __launch_bounds__(64) void fape_final(
    const float* __restrict__ S,
    const float* __restrict__ acfc,
    float* __restrict__ out, int b)
{
    const int i = blockIdx.x * 64 + threadIdx.x;
    if (i < b) {
        const float AC = fmaxf(acfc[2*i], 1.0f);
        const float FC = fmaxf(acfc[2*i + 1] * (float)NF, 1.0f);
        out[i] = S[i] / AC / FC * ZINV;
    }
}

extern "C" void kernel_launch(void* const* d_in, const int* in_sizes, int n_in,
                              void* d_out, int out_size, void* d_ws, size_t ws_size,
                              hipStream_t stream) {
    const float* predR   = (const float*)d_in[0];
    const float* predT   = (const float*)d_in[1];
    const float* predPos = (const float*)d_in[2];
    const float* atomM   = (const float*)d_in[3];
    const float* trueR   = (const float*)d_in[4];
    const float* trueT   = (const float*)d_in[5];
    const float* truePos = (const float*)d_in[6];
    const float* seqM    = (const float*)d_in[7];
    float* out = (float*)d_out;

    const int b = out_size;                   // fape_loss has shape (b,)
    const int N = in_sizes[7] / b;            // seq_mask is (b, N)
    const int totalFrames = b * N * NF;
    const int workBlocks  = (totalFrames / FT) * SPLIT;

    float* S    = (float*)d_ws;                      // b floats, accumulated
    float* acfc = (float*)((char*)d_ws + 4096);      // 2*b floats, plain stores

    hipMemsetAsync(S, 0, (size_t)b * sizeof(float), stream);

    fape_work<<<workBlocks + b, 256, 0, stream>>>(
        predR, predT, predPos, atomM, trueR, trueT, truePos, seqM,
        S, acfc, N, workBlocks);
    fape_final<<<(b + 63) / 64, 64, 0, stream>>>(S, acfc, out, b);
}

// Round 5
// 29.329 us; speedup vs baseline: 2.4745x; 1.2748x over previous
//
#include <hip/hip_runtime.h>

#define NF 8
#define NA 14
#define FT 4      // frames per work block (must divide NF)
#define SPLIT 2   // atom-range splits per frame group
#define D_CLAMP 10.0f
#define FAPE_EPS 1e-4f
#define ZINV 0.1f

// ws layout (floats): [0, workBlocks) partial | [workBlocks.. +2b) acfc
// Every element is rewritten on every launch -> no zeroing, replay-safe.
__global__ __launch_bounds__(256, 3) void fape_work(
    const float* __restrict__ predR,   // (b, N*NF, 3, 3)
    const float* __restrict__ predT,   // (b, N*NF, 3)
    const float* __restrict__ predPos, // (b, N*NA, 3)
    const float* __restrict__ atomMask,// (b, N*NA)
    const float* __restrict__ trueR,
    const float* __restrict__ trueT,
    const float* __restrict__ truePos,
    const float* __restrict__ seqMask, // (b, N)
    float* __restrict__ partial,       // [workBlocks]
    float* __restrict__ acfc,          // [2*b]
    int N, int workBlocks)
{
    const int tid = threadIdx.x;
    const int bid = blockIdx.x;
    const int nAtoms    = N * NA;
    const int nFramesPB = N * NF;

    __shared__ float sRed[4];
    __shared__ float sRed2[4];

    if (bid < workBlocks) {
        // ---------------- work block: FT frames x atom slice ----------------
        const int fgrp  = bid / SPLIT;
        const int sp    = bid - fgrp * SPLIT;
        const int fg0   = fgrp * FT;
        const int batch = fg0 / nFramesPB;
        const int res   = (fg0 - batch * nFramesPB) / NF; // uniform over the FT frames

        // Block-uniform frame constants; pre-negate true side so inner loop is pure FMA
        float rp[FT][9], rtn[FT][9], offn[FT][3];
#pragma unroll
        for (int k = 0; k < FT; ++k) {
            const float* Rp = predR + (size_t)(fg0 + k) * 9;
            const float* Rt = trueR + (size_t)(fg0 + k) * 9;
            const float* tp = predT + (size_t)(fg0 + k) * 3;
            const float* tt = trueT + (size_t)(fg0 + k) * 3;
#pragma unroll
            for (int i = 0; i < 9; ++i) { rp[k][i] = Rp[i]; rtn[k][i] = -Rt[i]; }
            const float tp0 = tp[0], tp1 = tp[1], tp2 = tp[2];
            const float tt0 = tt[0], tt1 = tt[1], tt2 = tt[2];
#pragma unroll
            for (int i = 0; i < 3; ++i) {
                offn[k][i] = -(rp[k][i]*tp0 + rp[k][3+i]*tp1 + rp[k][6+i]*tp2)
                             -(rtn[k][i]*tt0 + rtn[k][3+i]*tt1 + rtn[k][6+i]*tt2);
            }
        }

        const float* pP  = predPos  + (size_t)batch * nAtoms * 3;
        const float* tP  = truePos  + (size_t)batch * nAtoms * 3;
        const float* aMb = atomMask + (size_t)batch * nAtoms;
        const float* sMb = seqMask  + (size_t)batch * N;
        const float  w   = sMb[res];

        const int aBeg = (nAtoms * sp) / SPLIT;       // multiple of 4 for our shapes
        const int aEnd = (nAtoms * (sp + 1)) / SPLIT;

        float acc = 0.0f;

        auto pair = [&](float pp0, float pp1, float pp2,
                        float pt0, float pt1, float pt2, float m) {
#pragma unroll
            for (int k = 0; k < FT; ++k) {
                float d0 = offn[k][0] + rp[k][0]*pp0 + rp[k][3]*pp1 + rp[k][6]*pp2
                                      + rtn[k][0]*pt0 + rtn[k][3]*pt1 + rtn[k][6]*pt2;
                float d1 = offn[k][1] + rp[k][1]*pp0 + rp[k][4]*pp1 + rp[k][7]*pp2
                                      + rtn[k][1]*pt0 + rtn[k][4]*pt1 + rtn[k][7]*pt2;
                float d2 = offn[k][2] + rp[k][2]*pp0 + rp[k][5]*pp1 + rp[k][8]*pp2
                                      + rtn[k][2]*pt0 + rtn[k][5]*pt1 + rtn[k][8]*pt2;
                float ns = d0*d0 + d1*d1 + d2*d2 + FAPE_EPS;
                acc += fminf(__builtin_amdgcn_sqrtf(ns), D_CLAMP) * m;
            }
        };

        for (int a0 = aBeg + (tid << 2); a0 < aEnd; a0 += 1024) {
            const float4 P0 = *reinterpret_cast<const float4*>(pP + 3*a0);
            const float4 P1 = *reinterpret_cast<const float4*>(pP + 3*a0 + 4);
            const float4 P2 = *reinterpret_cast<const float4*>(pP + 3*a0 + 8);
            const float4 Q0 = *reinterpret_cast<const float4*>(tP + 3*a0);
            const float4 Q1 = *reinterpret_cast<const float4*>(tP + 3*a0 + 4);
            const float4 Q2 = *reinterpret_cast<const float4*>(tP + 3*a0 + 8);
            const float4 AM = *reinterpret_cast<const float4*>(aMb + a0);

            const int q   = a0 / NA;
            const int rem = a0 - q * NA;
            const float m0 = AM.x * sMb[q];
            const float m1 = AM.y * sMb[q + ((rem + 1) >= NA ? 1 : 0)];
            const float m2 = AM.z * sMb[q + ((rem + 2) >= NA ? 1 : 0)];
            const float m3 = AM.w * sMb[q + ((rem + 3) >= NA ? 1 : 0)];

            pair(P0.x, P0.y, P0.z,  Q0.x, Q0.y, Q0.z,  m0);
            pair(P0.w, P1.x, P1.y,  Q0.w, Q1.x, Q1.y,  m1);
            pair(P1.z, P1.w, P2.x,  Q1.z, Q1.w, Q2.x,  m2);
            pair(P2.y, P2.z, P2.w,  Q2.y, Q2.z, Q2.w,  m3);
        }

#pragma unroll
        for (int o = 32; o > 0; o >>= 1) acc += __shfl_down(acc, o, 64);
        if ((tid & 63) == 0) sRed[tid >> 6] = acc;
        __syncthreads();
        if (tid == 0) partial[bid] = (sRed[0] + sRed[1] + sRed[2] + sRed[3]) * w;
    } else {
        // -------------- mask block: atom_count & frame_count for one batch --
        const int batch = bid - workBlocks;
        const float* aMb = atomMask + (size_t)batch * nAtoms;
        const float* sMb = seqMask  + (size_t)batch * N;

        float ac = 0.0f, fc = 0.0f;
        for (int a0 = (tid << 2); a0 < nAtoms; a0 += 1024) {
            const float4 AM = *reinterpret_cast<const float4*>(aMb + a0);
            const int q   = a0 / NA;
            const int rem = a0 - q * NA;
            ac += AM.x * sMb[q]
                + AM.y * sMb[q + ((rem + 1) >= NA ? 1 : 0)]
                + AM.z * sMb[q + ((rem + 2) >= NA ? 1 : 0)]
                + AM.w * sMb[q + ((rem + 3) >= NA ? 1 : 0)];
        }
        for (int n = tid; n < N; n += 256) fc += sMb[n];

#pragma unroll
        for (int o = 32; o > 0; o >>= 1) {
            ac += __shfl_down(ac, o, 64);
            fc += __shfl_down(fc, o, 64);
        }
        if ((tid & 63) == 0) { sRed[tid >> 6] = ac; sRed2[tid >> 6] = fc; }
        __syncthreads();
        if (tid == 0) {
            acfc[2*batch]     = sRed[0] + sRed[1] + sRed[2] + sRed[3];
            acfc[2*batch + 1] = sRed2[0] + sRed2[1] + sRed2[2] + sRed2[3];
        }
    }
}

// Finisher: one block per batch, coalesced read of that batch's partials.
// Inter-dispatch ordering makes kernel 1's stores visible.
__global__ __launch_bounds__(256) void fape_final(
    const float* __restrict__ partial,
    const float* __restrict__ acfc,
    float* __restrict__ out, int blocksPerBatch)
{
    const int batch = blockIdx.x;
    const int tid   = threadIdx.x;
    const float* p  = partial + (size_t)batch * blocksPerBatch;

    float s = 0.0f;
    for (int i = tid; i < blocksPerBatch; i += 256) s += p[i];

#pragma unroll
    for (int o = 32; o > 0; o >>= 1) s += __shfl_down(s, o, 64);

    __shared__ float sRed[4];
    if ((tid & 63) == 0) sRed[tid >> 6] = s;
    __syncthreads();
    if (tid == 0) {
        const float S  = sRed[0] + sRed[1] + sRed[2] + sRed[3];
        const float AC = fmaxf(acfc[2*batch], 1.0f);
        const float FC = fmaxf(acfc[2*batch + 1] * (float)NF, 1.0f);
        out[batch] = S / AC / FC * ZINV;
    }
}

extern "C" void kernel_launch(void* const* d_in, const int* in_sizes, int n_in,
                              void* d_out, int out_size, void* d_ws, size_t ws_size,
                              hipStream_t stream) {
    const float* predR   = (const float*)d_in[0];
    const float* predT   = (const float*)d_in[1];
    const float* predPos = (const float*)d_in[2];
    const float* atomM   = (const float*)d_in[3];
    const float* trueR   = (const float*)d_in[4];
    const float* trueT   = (const float*)d_in[5];
    const float* truePos = (const float*)d_in[6];
    const float* seqM    = (const float*)d_in[7];
    float* out = (float*)d_out;

    const int b = out_size;                   // fape_loss has shape (b,)
    const int N = in_sizes[7] / b;            // seq_mask is (b, N)
    const int totalFrames = b * N * NF;
    const int workBlocks  = (totalFrames / FT) * SPLIT;
    const int blocksPerBatch = workBlocks / b;

    float* partial = (float*)d_ws;                                   // workBlocks floats
    float* acfc    = (float*)d_ws + workBlocks;                      // 2*b floats

    fape_work<<<workBlocks + b, 256, 0, stream>>>(
        predR, predT, predPos, atomM, trueR, trueT, truePos, seqM,
        partial, acfc, N, workBlocks);
    fape_final<<<b, 256, 0, stream>>>(partial, acfc, out, blocksPerBatch);
}